// Round 3
// baseline (289.097 us; speedup 1.0000x reference)
//
#include <hip/hip_runtime.h>
#include <math.h>

// EdgeSelector: B=32, N=64, D=64, H=4, E=256, HD=64
// out = [em (32,64,4,64) | sampled (32,64,4,64)] f32
// ws (floats): xn[131072] | T1[1572864] | T2[1572864] | bf16: Wb[768*128] w1b[64*64]

typedef __attribute__((ext_vector_type(8))) short short8;   // 8 bf16 = 4 VGPR
typedef __attribute__((ext_vector_type(4))) float f32x4;

__device__ __forceinline__ short f2b(float f) {  // RNE f32->bf16
  unsigned u = __builtin_bit_cast(unsigned, f);
  unsigned r = (u + 0x7FFFu + ((u >> 16) & 1u)) >> 16;
  return (short)r;
}

#define TS 72  // LDS row stride in shorts (144 B, 16B-aligned)

// LDS: R_A (Q then A2) | R_B (K then attn-w) | R_C (VT) | F (512 f32)
#define OFF_RA 0
#define OFF_RB 9216
#define OFF_RC 18432
#define OFF_F  27648
#define LDS_BYTES 29696
// sF: [0,192) T2h | [192,256) mask | [256,320) logits | [320,384) b1 | [384,448) w2

// ---------------- K1: xn = LN(x)*g+b, zeroed where row has no neighbors ----
__global__ __launch_bounds__(256) void k_node_ln(
    const float* __restrict__ x, const int* __restrict__ mask,
    const float* __restrict__ g, const float* __restrict__ bb,
    float* __restrict__ xn) {
  int tid = threadIdx.x;
  int row = blockIdx.x * 4 + (tid >> 6);
  int lane = tid & 63;
  float v = x[row * 64 + lane];
  float s = v;
#pragma unroll
  for (int m = 1; m < 64; m <<= 1) s += __shfl_xor(s, m, 64);
  float mean = s * (1.0f / 64.0f);
  float dv = v - mean;
  float s2 = dv * dv;
#pragma unroll
  for (int m = 1; m < 64; m <<= 1) s2 += __shfl_xor(s2, m, 64);
  float rstd = rsqrtf(s2 * (1.0f / 64.0f) + 1e-5f);
  float msum = (float)mask[row * 64 + lane];
#pragma unroll
  for (int m = 1; m < 64; m <<= 1) msum += __shfl_xor(msum, m, 64);
  float ped = (msum > 0.0f) ? 1.0f : 0.0f;
  xn[row * 64 + lane] = (dv * rstd * g[lane] + bb[lane]) * ped;
}

// ---------------- K2: T1[r,f]=W[f,0:64]·xn[r]; T2[r,f]=W[f,64:128]·xn[r]+bias[f]
__global__ __launch_bounds__(256) void k_t12(
    const float* __restrict__ xn, const float* __restrict__ W,
    const float* __restrict__ bias, float* __restrict__ T1, float* __restrict__ T2) {
  __shared__ __align__(16) float sx[8 * 64];
  int tid = threadIdx.x;
  int r0 = blockIdx.x * 8;
#pragma unroll
  for (int u = 0; u < 2; ++u) {
    int idx = tid + 256 * u;
    sx[idx] = xn[r0 * 64 + idx];
  }
  __syncthreads();
#pragma unroll
  for (int ff = 0; ff < 3; ++ff) {
    int f = tid + 256 * ff;
    float acc1[8], acc2[8];
#pragma unroll
    for (int r = 0; r < 8; ++r) { acc1[r] = 0.f; acc2[r] = 0.f; }
    for (int e4 = 0; e4 < 64; e4 += 4) {
      float4 wa = *(const float4*)&W[f * 256 + e4];
      float4 wb = *(const float4*)&W[f * 256 + 64 + e4];
#pragma unroll
      for (int r = 0; r < 8; ++r) {
        float4 xv = *(const float4*)&sx[r * 64 + e4];
        acc1[r] += wa.x * xv.x + wa.y * xv.y + wa.z * xv.z + wa.w * xv.w;
        acc2[r] += wb.x * xv.x + wb.y * xv.y + wb.z * xv.z + wb.w * xv.w;
      }
    }
    float bv = bias[f];
#pragma unroll
    for (int r = 0; r < 8; ++r) {
      T1[(r0 + r) * 768 + f] = acc1[r];
      T2[(r0 + r) * 768 + f] = acc2[r] + bv;
    }
  }
}

// ---------------- K_wb: bf16 copies of W[:,128:256] and w1 ----------------
__global__ __launch_bounds__(256) void k_wb(const float* __restrict__ W,
                                            const float* __restrict__ w1,
                                            short* __restrict__ Wb,
                                            short* __restrict__ w1b) {
  int idx = blockIdx.x * 256 + threadIdx.x;
  if (idx < 12288) {  // 768 rows x 16 granules of 8
    int f = idx >> 4, gi = idx & 15;
    const float* src = &W[(size_t)f * 256 + 128 + gi * 8];
    short8 o;
#pragma unroll
    for (int i = 0; i < 8; ++i) o[i] = f2b(src[i]);
    *(short8*)&Wb[f * 128 + gi * 8] = o;
  } else if (idx < 12288 + 512) {  // 64 x 8 granules
    int g2 = idx - 12288;
    int f = g2 >> 3, gi = g2 & 7;
    const float* src = &w1[f * 64 + gi * 8];
    short8 o;
#pragma unroll
    for (int i = 0; i < 8; ++i) o[i] = f2b(src[i]);
    *(short8*)&w1b[f * 64 + gi * 8] = o;
  }
}

// ---------------- K3: fused per-(b,t,h) ----------------
__global__ __launch_bounds__(256, 4) void k_main(
    const float* __restrict__ A, const int* __restrict__ mask,
    const float* __restrict__ gu, const float* __restrict__ leg,
    const float* __restrict__ leb, const float* __restrict__ b1g,
    const float* __restrict__ w2g, const float* __restrict__ b2g,
    const float* __restrict__ T1, const float* __restrict__ T2,
    const short* __restrict__ Wb, const short* __restrict__ w1b,
    float* __restrict__ out) {
  __shared__ __align__(16) unsigned char smem[LDS_BYTES];
  short* sQ  = (short*)(smem + OFF_RA);  // Q, then A2
  short* sA2 = (short*)(smem + OFF_RA);
  short* sK  = (short*)(smem + OFF_RB);  // K, then attn-w
  short* sWt = (short*)(smem + OFF_RB);
  short* sVT = (short*)(smem + OFF_RC);
  float* sF  = (float*)(smem + OFF_F);

  int tid = threadIdx.x;
  int bid0 = blockIdx.x;
  int wg = (bid0 & 7) * 1024 + (bid0 >> 3);  // XCD swizzle (8192 % 8 == 0)
  int h = wg & 3, t = (wg >> 2) & 63, b = wg >> 8;
  int bt = b * 64 + t;
  int wave = tid >> 6, lane = tid & 63, lr = lane & 15, lh = lane >> 4;

  // ---- stage small constants into sF ----
  if (tid < 192) sF[tid] = T2[bt * 768 + (tid >> 6) * 256 + h * 64 + (tid & 63)];
  else sF[192 + tid - 192] = (float)mask[bt * 64 + tid - 192];
  if (tid < 64) sF[320 + tid] = b1g[tid];
  else if (tid < 128) sF[384 + tid - 64] = w2g[tid - 64];

  // ---- An LN fully in registers: wave handles its 16 M-rows ----
  short8 af[4];
  {
    int m = wave * 16 + lr;
    const float* Ar = A + ((size_t)((b * 64 + m) * 64 + t)) * 128;
    float av[32];
    float s = 0.f, s2 = 0.f;
#pragma unroll
    for (int ks = 0; ks < 4; ++ks) {
      float4 u0 = *(const float4*)&Ar[ks * 32 + lh * 8];
      float4 u1 = *(const float4*)&Ar[ks * 32 + lh * 8 + 4];
      av[ks * 8 + 0] = u0.x; av[ks * 8 + 1] = u0.y;
      av[ks * 8 + 2] = u0.z; av[ks * 8 + 3] = u0.w;
      av[ks * 8 + 4] = u1.x; av[ks * 8 + 5] = u1.y;
      av[ks * 8 + 6] = u1.z; av[ks * 8 + 7] = u1.w;
      s += u0.x + u0.y + u0.z + u0.w + u1.x + u1.y + u1.z + u1.w;
      s2 += u0.x * u0.x + u0.y * u0.y + u0.z * u0.z + u0.w * u0.w +
            u1.x * u1.x + u1.y * u1.y + u1.z * u1.z + u1.w * u1.w;
    }
    s += __shfl_xor(s, 16, 64);  s += __shfl_xor(s, 32, 64);
    s2 += __shfl_xor(s2, 16, 64); s2 += __shfl_xor(s2, 32, 64);
    float mean = s * (1.0f / 128.0f);
    float var = s2 * (1.0f / 128.0f) - mean * mean;
    float rstd = rsqrtf(var + 1e-5f);
    float mv = (float)mask[bt * 64 + m];
#pragma unroll
    for (int ks = 0; ks < 4; ++ks) {
      float4 g0 = *(const float4*)&leg[ks * 32 + lh * 8];
      float4 g1 = *(const float4*)&leg[ks * 32 + lh * 8 + 4];
      float4 c0 = *(const float4*)&leb[ks * 32 + lh * 8];
      float4 c1 = *(const float4*)&leb[ks * 32 + lh * 8 + 4];
      float gg[8] = {g0.x, g0.y, g0.z, g0.w, g1.x, g1.y, g1.z, g1.w};
      float cc[8] = {c0.x, c0.y, c0.z, c0.w, c1.x, c1.y, c1.z, c1.w};
#pragma unroll
      for (int i = 0; i < 8; ++i)
        af[ks][i] = f2b(((av[ks * 8 + i] - mean) * rstd * gg[i] + cc[i]) * mv);
    }
  }
  __syncthreads();  // #0: sF ready

  // ---- projection p=0(q),1(k),2(v): B-frags direct from global Wb ----
#pragma unroll
  for (int p = 0; p < 3; ++p) {
    int Fbase = p * 256 + h * 64;
    float t1v[4][4];
#pragma unroll
    for (int nt = 0; nt < 4; ++nt)
#pragma unroll
      for (int r = 0; r < 4; ++r)
        t1v[nt][r] = T1[(size_t)(b * 64 + wave * 16 + lh * 4 + r) * 768 + Fbase + nt * 16 + lr];
    f32x4 acc[4] = {};
#pragma unroll
    for (int ks = 0; ks < 4; ++ks)
#pragma unroll
      for (int nt = 0; nt < 4; ++nt) {
        short8 bf = *(const short8*)&Wb[(size_t)(Fbase + nt * 16 + lr) * 128 + ks * 32 + lh * 8];
        acc[nt] = __builtin_amdgcn_mfma_f32_16x16x32_bf16(af[ks], bf, acc[nt], 0, 0, 0);
      }
#pragma unroll
    for (int nt = 0; nt < 4; ++nt)
#pragma unroll
      for (int r = 0; r < 4; ++r) {
        int m = wave * 16 + lh * 4 + r;
        int dcol = nt * 16 + lr;
        float val = acc[nt][r] + t1v[nt][r] + sF[p * 64 + dcol];
        if (p == 0)      sQ[m * TS + dcol] = f2b(val * 0.125f);  // * hd^-0.5
        else if (p == 1) sK[m * TS + dcol] = f2b(val);
        else             sVT[dcol * TS + m] = f2b(val);
      }
  }
  __syncthreads();  // #1: K, VT visible to all waves

  // ---- scores + masked softmax (exact ref algebra), weights kept in regs ----
  float wv[4][4];
  {
    f32x4 sc[4] = {};
#pragma unroll
    for (int ks = 0; ks < 2; ++ks) {
      short8 qf = *(const short8*)&sQ[(wave * 16 + lr) * TS + ks * 32 + lh * 8];
#pragma unroll
      for (int nt = 0; nt < 4; ++nt) {
        short8 kf = *(const short8*)&sK[(nt * 16 + lr) * TS + ks * 32 + lh * 8];
        sc[nt] = __builtin_amdgcn_mfma_f32_16x16x32_bf16(qf, kf, sc[nt], 0, 0, 0);
      }
    }
    float mk[4];
#pragma unroll
    for (int nt = 0; nt < 4; ++nt) mk[nt] = sF[192 + nt * 16 + lr];
#pragma unroll
    for (int r = 0; r < 4; ++r) {
      int j = wave * 16 + lh * 4 + r;
      float mj = sF[192 + j];
      float mx = fmaxf(fmaxf(sc[0][r], sc[1][r]), fmaxf(sc[2][r], sc[3][r]));
#pragma unroll
      for (int mm = 1; mm < 16; mm <<= 1) mx = fmaxf(mx, __shfl_xor(mx, mm, 64));
      float pv[4], Zf = 0.f, S = 0.f;
#pragma unroll
      for (int nt = 0; nt < 4; ++nt) {
        pv[nt] = expf(sc[nt][r] - mx);
        Zf += pv[nt];
        S += pv[nt] * mk[nt];
      }
#pragma unroll
      for (int mm = 1; mm < 16; mm <<= 1) {
        Zf += __shfl_xor(Zf, mm, 64);
        S += __shfl_xor(S, mm, 64);
      }
      // w = softmax*m3 renormed == p*mk*mj / (mj*S + 1e-10*Z)
      float inv = mj / (S + 1e-10f * Zf);
#pragma unroll
      for (int nt = 0; nt < 4; ++nt) wv[r][nt] = pv[nt] * mk[nt] * inv;
    }
  }
  __syncthreads();  // #2: all K reads done, R_B reusable
#pragma unroll
  for (int r = 0; r < 4; ++r)
#pragma unroll
    for (int nt = 0; nt < 4; ++nt)
      sWt[(wave * 16 + lh * 4 + r) * TS + nt * 16 + lr] = f2b(wv[r][nt]);
  __syncthreads();  // #3: attn weights visible

  // ---- A2[j,d] = sum_k w[j,k]*v[k,d]; write into R_A (Q dead) ----
  {
    f32x4 a2[4] = {};
#pragma unroll
    for (int ks = 0; ks < 2; ++ks) {
      short8 wf = *(const short8*)&sWt[(wave * 16 + lr) * TS + ks * 32 + lh * 8];
#pragma unroll
      for (int nt = 0; nt < 4; ++nt) {
        short8 vf = *(const short8*)&sVT[(nt * 16 + lr) * TS + ks * 32 + lh * 8];
        a2[nt] = __builtin_amdgcn_mfma_f32_16x16x32_bf16(wf, vf, a2[nt], 0, 0, 0);
      }
    }
#pragma unroll
    for (int nt = 0; nt < 4; ++nt)
#pragma unroll
      for (int r = 0; r < 4; ++r)
        sA2[(wave * 16 + lh * 4 + r) * TS + nt * 16 + lr] = f2b(a2[nt][r]);
  }
  // A2 rows are per-wave (written & read by the same wave) — no barrier needed

  // ---- hmid = relu(A2·w1^T + b1); logits[j] = hmid·w2 (w1 frags from global) ----
  {
    f32x4 hm[4] = {};
#pragma unroll
    for (int ks = 0; ks < 2; ++ks) {
      short8 a2f = *(const short8*)&sA2[(wave * 16 + lr) * TS + ks * 32 + lh * 8];
#pragma unroll
      for (int nt = 0; nt < 4; ++nt) {
        short8 wf = *(const short8*)&w1b[(nt * 16 + lr) * 64 + ks * 32 + lh * 8];
        hm[nt] = __builtin_amdgcn_mfma_f32_16x16x32_bf16(a2f, wf, hm[nt], 0, 0, 0);
      }
    }
    float b1v[4], w2v[4];
#pragma unroll
    for (int nt = 0; nt < 4; ++nt) {
      b1v[nt] = sF[320 + nt * 16 + lr];
      w2v[nt] = sF[384 + nt * 16 + lr];
    }
#pragma unroll
    for (int r = 0; r < 4; ++r) {
      float pp = 0.f;
#pragma unroll
      for (int nt = 0; nt < 4; ++nt)
        pp += fmaxf(hm[nt][r] + b1v[nt], 0.f) * w2v[nt];
#pragma unroll
      for (int mm = 1; mm < 16; mm <<= 1) pp += __shfl_xor(pp, mm, 64);
      if (lr == 0) sF[256 + wave * 16 + lh * 4 + r] = pp;
    }
  }
  __syncthreads();  // #4: logits ready

  // ---- em + gumbel + sampled (wave 0, lane j) ----
  if (tid < 64) {
    int j = tid;
    float l = sF[256 + j] + b2g[0];
    float mjv = sF[192 + j];
    float mx = l;
#pragma unroll
    for (int mm = 1; mm < 64; mm <<= 1) mx = fmaxf(mx, __shfl_xor(mx, mm, 64));
    float pv = expf(l - mx);
    float Z = pv;
#pragma unroll
    for (int mm = 1; mm < 64; mm <<= 1) Z += __shfl_xor(Z, mm, 64);
    float ep = (pv / Z) * mjv;
    float S = ep;
#pragma unroll
    for (int mm = 1; mm < 64; mm <<= 1) S += __shfl_xor(S, mm, 64);
    float em = ep / (S + 1e-10f);
    float u = gu[((size_t)bt * 4 + h) * 64 + j];
    float gg = -logf(-logf(u + 1e-10f) + 1e-10f);
    float l2 = logf(em + 1e-10f) + gg;  // TAU = 1
    float mx2 = l2;
#pragma unroll
    for (int mm = 1; mm < 64; mm <<= 1) mx2 = fmaxf(mx2, __shfl_xor(mx2, mm, 64));
    float p2 = expf(l2 - mx2);
    float Z2 = p2;
#pragma unroll
    for (int mm = 1; mm < 64; mm <<= 1) Z2 += __shfl_xor(Z2, mm, 64);
    float smp = p2 / Z2;
    size_t o = ((size_t)bt * 4 + h) * 64 + j;
    out[o] = em;
    out[524288 + o] = smp;
  }
}

extern "C" void kernel_launch(void* const* d_in, const int* in_sizes, int n_in,
                              void* d_out, int out_size, void* d_ws, size_t ws_size,
                              hipStream_t stream) {
  const float* x    = (const float*)d_in[0];
  const float* A    = (const float*)d_in[1];
  const int*   mask = (const int*)d_in[2];
  const float* gu   = (const float*)d_in[3];
  const float* lng  = (const float*)d_in[4];
  const float* lnb  = (const float*)d_in[5];
  const float* leg  = (const float*)d_in[6];
  const float* leb  = (const float*)d_in[7];
  const float* W    = (const float*)d_in[8];
  const float* bias = (const float*)d_in[9];
  const float* w1   = (const float*)d_in[10];
  const float* b1   = (const float*)d_in[11];
  const float* w2   = (const float*)d_in[12];
  const float* b2   = (const float*)d_in[13];
  float* out = (float*)d_out;
  float* ws  = (float*)d_ws;

  float* xn = ws;                        // 131072 floats
  float* T1 = xn + 131072;               // 1572864 floats
  float* T2 = T1 + 1572864;              // 1572864 floats
  short* Wb  = (short*)(T2 + 1572864);   // 98304 shorts
  short* w1b = Wb + 98304;               // 4096 shorts

  k_wb<<<50, 256, 0, stream>>>(W, w1, Wb, w1b);
  k_node_ln<<<512, 256, 0, stream>>>(x, mask, lng, lnb, xn);
  k_t12<<<256, 256, 0, stream>>>(xn, W, bias, T1, T2);
  k_main<<<8192, 256, 0, stream>>>(A, mask, gu, leg, leb, b1, w2, b2,
                                   T1, T2, Wb, w1b, out);
}

// Round 4
// 183.518 us; speedup vs baseline: 1.5753x; 1.5753x over previous
//
#include <hip/hip_runtime.h>
#include <math.h>

// EdgeSelector: B=32, N=64, D=64, H=4, E=256, HD=64
// out = [em (32,64,4,64) | sampled (32,64,4,64)] f32
// ws (floats): xn[131072] | T1[1572864] | T2[1572864] | bf16: Wb[768*128] w1b[64*64]

typedef __attribute__((ext_vector_type(8))) short short8;   // 8 bf16 = 4 VGPR
typedef __attribute__((ext_vector_type(4))) float f32x4;

__device__ __forceinline__ short f2b(float f) {  // RNE f32->bf16
  unsigned u = __builtin_bit_cast(unsigned, f);
  unsigned r = (u + 0x7FFFu + ((u >> 16) & 1u)) >> 16;
  return (short)r;
}

#define WCS 136  // Wc row stride in shorts (272 B; 68 dwords ≡ 4 mod 32 banks -> even spread)
#define TS  72   // q/k/vT/A2/w row stride in shorts (144 B)

// LDS: WC (Wc, then attn-w) | RA (Q then A2) | RB (K) | RC (VT) | F (448 f32)
#define OFF_WC 0
#define OFF_RA 17408
#define OFF_RB 26624
#define OFF_RC 35840
#define OFF_F  45056
#define LDS_BYTES 46848
// sF: [0,192) T2h | [192,256) mask | [256,320) logits | [320,384) b1 | [384,448) w2

// ---------------- K1: xn = LN(x)*g+b, zeroed where row has no neighbors ----
__global__ __launch_bounds__(256) void k_node_ln(
    const float* __restrict__ x, const int* __restrict__ mask,
    const float* __restrict__ g, const float* __restrict__ bb,
    float* __restrict__ xn) {
  int tid = threadIdx.x;
  int row = blockIdx.x * 4 + (tid >> 6);
  int lane = tid & 63;
  float v = x[row * 64 + lane];
  float s = v;
#pragma unroll
  for (int m = 1; m < 64; m <<= 1) s += __shfl_xor(s, m, 64);
  float mean = s * (1.0f / 64.0f);
  float dv = v - mean;
  float s2 = dv * dv;
#pragma unroll
  for (int m = 1; m < 64; m <<= 1) s2 += __shfl_xor(s2, m, 64);
  float rstd = rsqrtf(s2 * (1.0f / 64.0f) + 1e-5f);
  float msum = (float)mask[row * 64 + lane];
#pragma unroll
  for (int m = 1; m < 64; m <<= 1) msum += __shfl_xor(msum, m, 64);
  float ped = (msum > 0.0f) ? 1.0f : 0.0f;
  xn[row * 64 + lane] = (dv * rstd * g[lane] + bb[lane]) * ped;
}

// ---------------- K2: T1[r,f]=W[f,0:64]·xn[r]; T2[r,f]=W[f,64:128]·xn[r]+bias[f]
__global__ __launch_bounds__(256) void k_t12(
    const float* __restrict__ xn, const float* __restrict__ W,
    const float* __restrict__ bias, float* __restrict__ T1, float* __restrict__ T2) {
  __shared__ __align__(16) float sx[8 * 64];
  int tid = threadIdx.x;
  int r0 = blockIdx.x * 8;
#pragma unroll
  for (int u = 0; u < 2; ++u) {
    int idx = tid + 256 * u;
    sx[idx] = xn[r0 * 64 + idx];
  }
  __syncthreads();
#pragma unroll
  for (int ff = 0; ff < 3; ++ff) {
    int f = tid + 256 * ff;
    float acc1[8], acc2[8];
#pragma unroll
    for (int r = 0; r < 8; ++r) { acc1[r] = 0.f; acc2[r] = 0.f; }
    for (int e4 = 0; e4 < 64; e4 += 4) {
      float4 wa = *(const float4*)&W[f * 256 + e4];
      float4 wb = *(const float4*)&W[f * 256 + 64 + e4];
#pragma unroll
      for (int r = 0; r < 8; ++r) {
        float4 xv = *(const float4*)&sx[r * 64 + e4];
        acc1[r] += wa.x * xv.x + wa.y * xv.y + wa.z * xv.z + wa.w * xv.w;
        acc2[r] += wb.x * xv.x + wb.y * xv.y + wb.z * xv.z + wb.w * xv.w;
      }
    }
    float bv = bias[f];
#pragma unroll
    for (int r = 0; r < 8; ++r) {
      T1[(r0 + r) * 768 + f] = acc1[r];
      T2[(r0 + r) * 768 + f] = acc2[r] + bv;
    }
  }
}

// ---------------- K_wb: bf16 copies of W[:,128:256] and w1 ----------------
__global__ __launch_bounds__(256) void k_wb(const float* __restrict__ W,
                                            const float* __restrict__ w1,
                                            short* __restrict__ Wb,
                                            short* __restrict__ w1b) {
  int idx = blockIdx.x * 256 + threadIdx.x;
  if (idx < 12288) {  // 768 rows x 16 granules of 8
    int f = idx >> 4, gi = idx & 15;
    const float* src = &W[(size_t)f * 256 + 128 + gi * 8];
    short8 o;
#pragma unroll
    for (int i = 0; i < 8; ++i) o[i] = f2b(src[i]);
    *(short8*)&Wb[f * 128 + gi * 8] = o;
  } else if (idx < 12288 + 512) {  // 64 x 8 granules
    int g2 = idx - 12288;
    int f = g2 >> 3, gi = g2 & 7;
    const float* src = &w1[f * 64 + gi * 8];
    short8 o;
#pragma unroll
    for (int i = 0; i < 8; ++i) o[i] = f2b(src[i]);
    *(short8*)&w1b[f * 64 + gi * 8] = o;
  }
}

// ---------------- K3: fused per-(b,t,h) ----------------
__global__ __launch_bounds__(256, 3) void k_main(
    const float* __restrict__ A, const int* __restrict__ mask,
    const float* __restrict__ gu, const float* __restrict__ leg,
    const float* __restrict__ leb, const float* __restrict__ b1g,
    const float* __restrict__ w2g, const float* __restrict__ b2g,
    const float* __restrict__ T1, const float* __restrict__ T2,
    const short* __restrict__ Wb, const short* __restrict__ w1b,
    float* __restrict__ out) {
  __shared__ __align__(16) unsigned char smem[LDS_BYTES];
  short* sWc = (short*)(smem + OFF_WC);  // Wc staging; attn-w after proj
  short* sWt = (short*)(smem + OFF_WC);
  short* sQ  = (short*)(smem + OFF_RA);  // Q, then A2
  short* sA2 = (short*)(smem + OFF_RA);
  short* sK  = (short*)(smem + OFF_RB);
  short* sVT = (short*)(smem + OFF_RC);
  float* sF  = (float*)(smem + OFF_F);

  int tid = threadIdx.x;
  int bid0 = blockIdx.x;
  int wg = (bid0 & 7) * 1024 + (bid0 >> 3);  // XCD swizzle (8192 % 8 == 0)
  int h = wg & 3, t = (wg >> 2) & 63, b = wg >> 8;
  int bt = b * 64 + t;
  int wave = tid >> 6, lane = tid & 63, lr = lane & 15, lh = lane >> 4;

  // ---- stage small constants into sF ----
  if (tid < 192) sF[tid] = T2[bt * 768 + (tid >> 6) * 256 + h * 64 + (tid & 63)];
  else sF[192 + tid - 192] = (float)mask[bt * 64 + tid - 192];
  if (tid < 64) sF[320 + tid] = b1g[tid];
  else if (tid < 128) sF[384 + tid - 64] = w2g[tid - 64];

  // ---- An LN fully in registers: wave handles its 16 M-rows ----
  short8 af[4];
  {
    int m = wave * 16 + lr;
    const float* Ar = A + ((size_t)((b * 64 + m) * 64 + t)) * 128;
    float av[32];
    float s = 0.f, s2 = 0.f;
#pragma unroll
    for (int ks = 0; ks < 4; ++ks) {
      float4 u0 = *(const float4*)&Ar[ks * 32 + lh * 8];
      float4 u1 = *(const float4*)&Ar[ks * 32 + lh * 8 + 4];
      av[ks * 8 + 0] = u0.x; av[ks * 8 + 1] = u0.y;
      av[ks * 8 + 2] = u0.z; av[ks * 8 + 3] = u0.w;
      av[ks * 8 + 4] = u1.x; av[ks * 8 + 5] = u1.y;
      av[ks * 8 + 6] = u1.z; av[ks * 8 + 7] = u1.w;
      s += u0.x + u0.y + u0.z + u0.w + u1.x + u1.y + u1.z + u1.w;
      s2 += u0.x * u0.x + u0.y * u0.y + u0.z * u0.z + u0.w * u0.w +
            u1.x * u1.x + u1.y * u1.y + u1.z * u1.z + u1.w * u1.w;
    }
    s += __shfl_xor(s, 16, 64);  s += __shfl_xor(s, 32, 64);
    s2 += __shfl_xor(s2, 16, 64); s2 += __shfl_xor(s2, 32, 64);
    float mean = s * (1.0f / 128.0f);
    float var = s2 * (1.0f / 128.0f) - mean * mean;
    float rstd = rsqrtf(var + 1e-5f);
    float mv = (float)mask[bt * 64 + m];
#pragma unroll
    for (int ks = 0; ks < 4; ++ks) {
      float4 g0 = *(const float4*)&leg[ks * 32 + lh * 8];
      float4 g1 = *(const float4*)&leg[ks * 32 + lh * 8 + 4];
      float4 c0 = *(const float4*)&leb[ks * 32 + lh * 8];
      float4 c1 = *(const float4*)&leb[ks * 32 + lh * 8 + 4];
      float gg[8] = {g0.x, g0.y, g0.z, g0.w, g1.x, g1.y, g1.z, g1.w};
      float cc[8] = {c0.x, c0.y, c0.z, c0.w, c1.x, c1.y, c1.z, c1.w};
#pragma unroll
      for (int i = 0; i < 8; ++i)
        af[ks][i] = f2b(((av[ks * 8 + i] - mean) * rstd * gg[i] + cc[i]) * mv);
    }
  }

  // ---- projection p=0(q),1(k),2(v): Wc staged in LDS from bf16 Wb ----
  for (int p = 0; p < 3; ++p) {
    int Fbase = p * 256 + h * 64;
    // stage Wc: 64 rows x 128 shorts (pure copy, coalesced 16B granules)
#pragma unroll
    for (int u = 0; u < 4; ++u) {
      int idx = tid + 256 * u;
      int dR = idx >> 4, gi = idx & 15;
      *(short8*)&sWc[dR * WCS + gi * 8] =
          *(const short8*)&Wb[(size_t)(Fbase + dR) * 128 + gi * 8];
    }
    // T1 prefetch (global, overlaps barrier + MFMA)
    float t1v[4][4];
#pragma unroll
    for (int nt = 0; nt < 4; ++nt)
#pragma unroll
      for (int r = 0; r < 4; ++r)
        t1v[nt][r] = T1[(size_t)(b * 64 + wave * 16 + lh * 4 + r) * 768 + Fbase + nt * 16 + lr];
    __syncthreads();  // staging (and sF on p=0) visible
    f32x4 acc[4] = {};
#pragma unroll
    for (int ks = 0; ks < 4; ++ks)
#pragma unroll
      for (int nt = 0; nt < 4; ++nt) {
        short8 bf = *(const short8*)&sWc[(nt * 16 + lr) * WCS + ks * 32 + lh * 8];
        acc[nt] = __builtin_amdgcn_mfma_f32_16x16x32_bf16(af[ks], bf, acc[nt], 0, 0, 0);
      }
#pragma unroll
    for (int nt = 0; nt < 4; ++nt)
#pragma unroll
      for (int r = 0; r < 4; ++r) {
        int m = wave * 16 + lh * 4 + r;
        int dcol = nt * 16 + lr;
        float val = acc[nt][r] + t1v[nt][r] + sF[p * 64 + dcol];
        if (p == 0)      sQ[m * TS + dcol] = f2b(val * 0.125f);  // * hd^-0.5
        else if (p == 1) sK[m * TS + dcol] = f2b(val);
        else             sVT[dcol * TS + m] = f2b(val);
      }
    __syncthreads();  // Wc reads done (next staging may overwrite); K/VT visible after p=2
  }

  // ---- scores + masked softmax (exact ref algebra) ----
  float wv[4][4];
  {
    f32x4 sc[4] = {};
#pragma unroll
    for (int ks = 0; ks < 2; ++ks) {
      short8 qf = *(const short8*)&sQ[(wave * 16 + lr) * TS + ks * 32 + lh * 8];
#pragma unroll
      for (int nt = 0; nt < 4; ++nt) {
        short8 kf = *(const short8*)&sK[(nt * 16 + lr) * TS + ks * 32 + lh * 8];
        sc[nt] = __builtin_amdgcn_mfma_f32_16x16x32_bf16(qf, kf, sc[nt], 0, 0, 0);
      }
    }
    float mk[4];
#pragma unroll
    for (int nt = 0; nt < 4; ++nt) mk[nt] = sF[192 + nt * 16 + lr];
#pragma unroll
    for (int r = 0; r < 4; ++r) {
      int j = wave * 16 + lh * 4 + r;
      float mj = sF[192 + j];
      float mx = fmaxf(fmaxf(sc[0][r], sc[1][r]), fmaxf(sc[2][r], sc[3][r]));
#pragma unroll
      for (int mm = 1; mm < 16; mm <<= 1) mx = fmaxf(mx, __shfl_xor(mx, mm, 64));
      float pv[4], Zf = 0.f, S = 0.f;
#pragma unroll
      for (int nt = 0; nt < 4; ++nt) {
        pv[nt] = expf(sc[nt][r] - mx);
        Zf += pv[nt];
        S += pv[nt] * mk[nt];
      }
#pragma unroll
      for (int mm = 1; mm < 16; mm <<= 1) {
        Zf += __shfl_xor(Zf, mm, 64);
        S += __shfl_xor(S, mm, 64);
      }
      // w = softmax*m3 renormed == p*mk*mj / (mj*S + 1e-10*Z)
      float inv = mj / (S + 1e-10f * Zf);
#pragma unroll
      for (int nt = 0; nt < 4; ++nt) wv[r][nt] = pv[nt] * mk[nt] * inv;
    }
  }
  // ---- transpose w via LDS (Wc region, dead): same-wave rows, no barrier ----
#pragma unroll
  for (int r = 0; r < 4; ++r)
#pragma unroll
    for (int nt = 0; nt < 4; ++nt)
      sWt[(wave * 16 + lh * 4 + r) * TS + nt * 16 + lr] = f2b(wv[r][nt]);

  // ---- A2[j,d] = sum_k w[j,k]*v[k,d]; write into R_A (Q dead, same-wave) ----
  {
    f32x4 a2[4] = {};
#pragma unroll
    for (int ks = 0; ks < 2; ++ks) {
      short8 wf = *(const short8*)&sWt[(wave * 16 + lr) * TS + ks * 32 + lh * 8];
#pragma unroll
      for (int nt = 0; nt < 4; ++nt) {
        short8 vf = *(const short8*)&sVT[(nt * 16 + lr) * TS + ks * 32 + lh * 8];
        a2[nt] = __builtin_amdgcn_mfma_f32_16x16x32_bf16(wf, vf, a2[nt], 0, 0, 0);
      }
    }
#pragma unroll
    for (int nt = 0; nt < 4; ++nt)
#pragma unroll
      for (int r = 0; r < 4; ++r)
        sA2[(wave * 16 + lh * 4 + r) * TS + nt * 16 + lr] = f2b(a2[nt][r]);
  }

  // ---- hmid = relu(A2·w1^T + b1); logits[j] = hmid·w2 (w1 frags from global) ----
  {
    f32x4 hm[4] = {};
#pragma unroll
    for (int ks = 0; ks < 2; ++ks) {
      short8 a2f = *(const short8*)&sA2[(wave * 16 + lr) * TS + ks * 32 + lh * 8];
#pragma unroll
      for (int nt = 0; nt < 4; ++nt) {
        short8 wf = *(const short8*)&w1b[(nt * 16 + lr) * 64 + ks * 32 + lh * 8];
        hm[nt] = __builtin_amdgcn_mfma_f32_16x16x32_bf16(a2f, wf, hm[nt], 0, 0, 0);
      }
    }
    float b1v[4], w2v[4];
#pragma unroll
    for (int nt = 0; nt < 4; ++nt) {
      b1v[nt] = sF[320 + nt * 16 + lr];
      w2v[nt] = sF[384 + nt * 16 + lr];
    }
#pragma unroll
    for (int r = 0; r < 4; ++r) {
      float pp = 0.f;
#pragma unroll
      for (int nt = 0; nt < 4; ++nt)
        pp += fmaxf(hm[nt][r] + b1v[nt], 0.f) * w2v[nt];
#pragma unroll
      for (int mm = 1; mm < 16; mm <<= 1) pp += __shfl_xor(pp, mm, 64);
      if (lr == 0) sF[256 + wave * 16 + lh * 4 + r] = pp;
    }
  }
  __syncthreads();  // logits ready

  // ---- em + gumbel + sampled (wave 0, lane j) ----
  if (tid < 64) {
    int j = tid;
    float l = sF[256 + j] + b2g[0];
    float mjv = sF[192 + j];
    float mx = l;
#pragma unroll
    for (int mm = 1; mm < 64; mm <<= 1) mx = fmaxf(mx, __shfl_xor(mx, mm, 64));
    float pv = expf(l - mx);
    float Z = pv;
#pragma unroll
    for (int mm = 1; mm < 64; mm <<= 1) Z += __shfl_xor(Z, mm, 64);
    float ep = (pv / Z) * mjv;
    float S = ep;
#pragma unroll
    for (int mm = 1; mm < 64; mm <<= 1) S += __shfl_xor(S, mm, 64);
    float em = ep / (S + 1e-10f);
    float u = gu[((size_t)bt * 4 + h) * 64 + j];
    float gg = -logf(-logf(u + 1e-10f) + 1e-10f);
    float l2 = logf(em + 1e-10f) + gg;  // TAU = 1
    float mx2 = l2;
#pragma unroll
    for (int mm = 1; mm < 64; mm <<= 1) mx2 = fmaxf(mx2, __shfl_xor(mx2, mm, 64));
    float p2 = expf(l2 - mx2);
    float Z2 = p2;
#pragma unroll
    for (int mm = 1; mm < 64; mm <<= 1) Z2 += __shfl_xor(Z2, mm, 64);
    float smp = p2 / Z2;
    size_t o = ((size_t)bt * 4 + h) * 64 + j;
    out[o] = em;
    out[524288 + o] = smp;
  }
}

extern "C" void kernel_launch(void* const* d_in, const int* in_sizes, int n_in,
                              void* d_out, int out_size, void* d_ws, size_t ws_size,
                              hipStream_t stream) {
  const float* x    = (const float*)d_in[0];
  const float* A    = (const float*)d_in[1];
  const int*   mask = (const int*)d_in[2];
  const float* gu   = (const float*)d_in[3];
  const float* lng  = (const float*)d_in[4];
  const float* lnb  = (const float*)d_in[5];
  const float* leg  = (const float*)d_in[6];
  const float* leb  = (const float*)d_in[7];
  const float* W    = (const float*)d_in[8];
  const float* bias = (const float*)d_in[9];
  const float* w1   = (const float*)d_in[10];
  const float* b1   = (const float*)d_in[11];
  const float* w2   = (const float*)d_in[12];
  const float* b2   = (const float*)d_in[13];
  float* out = (float*)d_out;
  float* ws  = (float*)d_ws;

  float* xn = ws;                        // 131072 floats
  float* T1 = xn + 131072;               // 1572864 floats
  float* T2 = T1 + 1572864;              // 1572864 floats
  short* Wb  = (short*)(T2 + 1572864);   // 98304 shorts
  short* w1b = Wb + 98304;               // 4096 shorts

  k_wb<<<50, 256, 0, stream>>>(W, w1, Wb, w1b);
  k_node_ln<<<512, 256, 0, stream>>>(x, mask, lng, lnb, xn);
  k_t12<<<256, 256, 0, stream>>>(xn, W, bias, T1, T2);
  k_main<<<8192, 256, 0, stream>>>(A, mask, gu, leg, leb, b1, w2, b2,
                                   T1, T2, Wb, w1b, out);
}